// Round 8
// baseline (7365.920 us; speedup 1.0000x reference)
//
#include <hip/hip_runtime.h>
#include <hip/hip_bf16.h>

// BiLSTM-CRF tagger, MI355X. Round 8: hint-free direct tagged-data polling.
//   K2 fused embed-gather + xg GEMM (fp32 compute, bf16 store)
//   K3 LSTM recurrence: 96 blocks (48/dir) x 1024 thr (16 waves, 1 h-elem/wave).
//      Producers fire-and-forget ONE tagged u64 {tag,f32 h} per wave (parity
//      double-buffer). Consumers (wave 0) poll the 768 tagged words directly
//      with SELECTIVE re-reads (only stale words re-fetched per round) -- the
//      poll round that sees the last producer IS the data read: no hint hop,
//      no ack serialization, no stale-burst retries (round 7's hidden cost).
//      Two __syncthreads()/step restore the intra-block gate (fixes the
//      wave-0-runs-ahead hbuf race) and replace the lflag spin.
//   K4 head + log_softmax -> K5 wave-synchronous Viterbi.

#define SEQ  2048
#define DINW 496
#define HDIM 768
#define G4   3072
#define CDIM 13
#define NWG  48           // workgroups per direction (2*NWG = 96 blocks)
#define JPW  16           // h elements per workgroup (one per wave)
#define DATA_SPIN (1u << 14)

__device__ __forceinline__ float sigf(float x) { return 1.0f / (1.0f + __expf(-x)); }
__device__ __forceinline__ float tanhf_fast(float x) {
    float ax = fabsf(x);
    float e  = __expf(-2.0f * ax);
    float t  = (1.0f - e) / (1.0f + e);
    return copysignf(t, x);
}

// ---------------- K2: xg = [we[x],ce[casing],pe[pos]] @ Wih^T + b  (bf16 out)
__global__ __launch_bounds__(256) void k_gemm_xg(
    const int* __restrict__ x, const int* __restrict__ casing, const int* __restrict__ pos,
    const float* __restrict__ we, const float* __restrict__ ce, const float* __restrict__ pe,
    const float* __restrict__ Wih_f, const float* __restrict__ b_f,
    const float* __restrict__ Wih_b, const float* __restrict__ b_b,
    __hip_bfloat16* __restrict__ xg_f, __hip_bfloat16* __restrict__ xg_b)
{
    __shared__ float As[16][68];
    __shared__ float Bs[16][68];
    int dir = blockIdx.z;
    const float* B    = dir ? Wih_b : Wih_f;
    const float* bias = dir ? b_b   : b_f;
    __hip_bfloat16* C = dir ? xg_b  : xg_f;
    int n0 = blockIdx.x * 64, m0 = blockIdx.y * 64;
    int tid = threadIdx.x;
    int tx = tid & 15, ty = tid >> 4;
    int lr = tid >> 2, lk = (tid & 3) * 4;

    int m = m0 + lr;
    const float* arow_w = we + (size_t)x[m] * 400;
    const float* arow_c = ce + (size_t)casing[m] * 32;
    const float* arow_p = pe + (size_t)pos[m] * 64;

    float acc[4][4] = {};
    for (int k0 = 0; k0 < DINW; k0 += 16) {
        int c0 = k0 + lk;
        float4 a;
        if (c0 < 400)      a = *(const float4*)(arow_w + c0);
        else if (c0 < 432) a = *(const float4*)(arow_c + (c0 - 400));
        else               a = *(const float4*)(arow_p + (c0 - 432));
        float4 b = *(const float4*)(B + (size_t)(n0 + lr) * DINW + c0);
        __syncthreads();
        As[lk + 0][lr] = a.x; As[lk + 1][lr] = a.y; As[lk + 2][lr] = a.z; As[lk + 3][lr] = a.w;
        Bs[lk + 0][lr] = b.x; Bs[lk + 1][lr] = b.y; Bs[lk + 2][lr] = b.z; Bs[lk + 3][lr] = b.w;
        __syncthreads();
        #pragma unroll
        for (int k = 0; k < 16; k++) {
            float4 av = *(const float4*)&As[k][ty * 4];
            float4 bv = *(const float4*)&Bs[k][tx * 4];
            float aa[4] = {av.x, av.y, av.z, av.w};
            float bb[4] = {bv.x, bv.y, bv.z, bv.w};
            #pragma unroll
            for (int i = 0; i < 4; i++)
                #pragma unroll
                for (int jj = 0; jj < 4; jj++)
                    acc[i][jj] += aa[i] * bb[jj];
        }
    }
    float4 bs4 = *(const float4*)(bias + n0 + tx * 4);
    float bb4[4] = {bs4.x, bs4.y, bs4.z, bs4.w};
    #pragma unroll
    for (int i = 0; i < 4; i++) {
        union { __hip_bfloat16 h[4]; ushort4 u; } cv;
        #pragma unroll
        for (int jj = 0; jj < 4; jj++)
            cv.h[jj] = __float2bfloat16(acc[i][jj] + bb4[jj]);
        *(ushort4*)(C + (size_t)(m0 + ty * 4 + i) * G4 + n0 + tx * 4) = cv.u;
    }
}

// ------------------------------------------------------- K3: LSTM recurrence
// msg[dir][parity][768] u64 {tag<<32 | f32bits(h)}: h(t) -> parity t&1, tag t+1.
// Consumer step t polls parity (t&1)^1 for tag == t with selective re-reads.
// Overwrite-safety/deadlock-freedom: P stores tag t+2 only after P's step-t+1
// poll saw ALL tag-(t+1) words; a block's words carry tag t+1 only after that
// block passed its step-t B1 (i.e. fully consumed tag t). So every consumer of
// tag t finishes before tag t is overwritten, and the tag each poller waits
// for is always eventually produced.
__global__ __launch_bounds__(1024) void k_lstm(
    const __hip_bfloat16* __restrict__ xg_f, const __hip_bfloat16* __restrict__ xg_b,
    const float* __restrict__ Whh_f, const float* __restrict__ Whh_b,
    const float* __restrict__ h0, const float* __restrict__ c0v,
    float* __restrict__ hs_f, float* __restrict__ hs_b,
    unsigned long long* __restrict__ msg, unsigned* __restrict__ abortw)
{
    __shared__ float hbuf[2][HDIM];
    __shared__ unsigned sdead;

    int wg = blockIdx.x;
    int dir = wg & 1, slot = wg >> 1;          // slot 0..47
    const __hip_bfloat16* xg = dir ? xg_b : xg_f;
    const float* Whh = dir ? Whh_b : Whh_f;
    float* hs        = dir ? hs_b  : hs_f;
    unsigned long long* mdir = msg + (size_t)dir * 2 * HDIM;

    int tid = threadIdx.x, lane = tid & 63, wv = tid >> 6;   // wv 0..15
    int q = lane >> 4, gl = lane & 15;
    int j = slot * JPW + wv;

    // this lane's Whh slice: row q*768+j, cols gl*4 + m*64 + e
    float w[48];
    const float* wr = Whh + (size_t)(q * HDIM + j) * HDIM;
    #pragma unroll
    for (int m = 0; m < 12; m++) {
        float4 f4 = *(const float4*)(wr + gl * 4 + m * 64);
        w[m * 4 + 0] = f4.x; w[m * 4 + 1] = f4.y;
        w[m * 4 + 2] = f4.z; w[m * 4 + 3] = f4.w;
    }
    float cst = c0v[dir * HDIM + j];

    if (tid == 0) sdead = 0;

    for (int t = 0; t < SEQ; t++) {
        int xrow = dir ? (SEQ - 1 - t) : t;
        const __hip_bfloat16* xga = xg + (size_t)xrow * G4 + j;
        float xv0 = __bfloat162float(xga[0]);
        float xv1 = __bfloat162float(xga[HDIM]);
        float xv2 = __bfloat162float(xga[2 * HDIM]);
        float xv3 = __bfloat162float(xga[3 * HDIM]);

        int par = (t & 1) ^ 1;   // parity slot holding h(t-1)

        if (wv == 0) {
            if (t == 0) {
                #pragma unroll
                for (int m = 0; m < 12; m++)
                    hbuf[1][m * 64 + lane] = h0[dir * HDIM + m * 64 + lane];
            } else {
                // direct tagged-data poll, selective re-reads of stale words
                const unsigned long long* g = mdir + (size_t)par * HDIM;
                unsigned long long vals[12];
                unsigned freshm = 0;       // bit m: word m's tag == t
                unsigned rounds = 0;
                bool dead = false;
                for (;;) {
                    #pragma unroll
                    for (int m = 0; m < 12; m++)
                        if (!(freshm & (1u << m)))
                            vals[m] = __hip_atomic_load(&g[m * 64 + lane],
                                        __ATOMIC_RELAXED, __HIP_MEMORY_SCOPE_AGENT);
                    #pragma unroll
                    for (int m = 0; m < 12; m++)
                        if ((unsigned)(vals[m] >> 32) == (unsigned)t)
                            freshm |= (1u << m);
                    if (__all(freshm == 0xFFFu)) break;
                    unsigned ab = __hip_atomic_load(abortw,
                                    __ATOMIC_RELAXED, __HIP_MEMORY_SCOPE_AGENT);
                    if (ab || ++rounds >= DATA_SPIN) { dead = true; break; }
                }
                #pragma unroll
                for (int m = 0; m < 12; m++) {
                    union { unsigned u; float f; } cvt;
                    cvt.u = (unsigned)vals[m];
                    hbuf[par][m * 64 + lane] = cvt.f;
                }
                if (dead && lane == 0) {   // cascade shutdown, bounded everywhere
                    __hip_atomic_store(abortw, 1u,
                                       __ATOMIC_RELAXED, __HIP_MEMORY_SCOPE_AGENT);
                    sdead = 1;
                }
            }
        }

        __syncthreads();           // B1: hbuf ready (and sdead visible)
        if (sdead) break;          // block-uniform bail

        // matvec slice over this lane's 48 columns from LDS
        float acc = 0.f;
        #pragma unroll
        for (int m = 0; m < 12; m++) {
            float4 f4 = *(const float4*)&hbuf[par][gl * 4 + m * 64];
            acc += w[m * 4 + 0] * f4.x + w[m * 4 + 1] * f4.y
                 + w[m * 4 + 2] * f4.z + w[m * 4 + 3] * f4.w;
        }
        acc += __shfl_xor(acc, 1);
        acc += __shfl_xor(acc, 2);
        acc += __shfl_xor(acc, 4);
        acc += __shfl_xor(acc, 8);
        float si = __shfl(acc, 0),  sf = __shfl(acc, 16);
        float sg = __shfl(acc, 32), so = __shfl(acc, 48);

        float gi = sigf(xv0 + si), gf = sigf(xv1 + sf);
        float gg = tanhf_fast(xv2 + sg), go = sigf(xv3 + so);
        cst = gf * cst + gi * gg;
        float h = go * tanhf_fast(cst);

        if (lane == 0) {
            int hrow = dir ? (SEQ - 1 - t) : t;
            hs[(size_t)hrow * HDIM + j] = h;          // for K4 (cross-dispatch)
            union { float f; unsigned u; } cvt; cvt.f = h;
            unsigned long long word = ((unsigned long long)(unsigned)(t + 1) << 32)
                                    | (unsigned long long)cvt.u;
            __hip_atomic_store(&mdir[(size_t)(t & 1) * HDIM + j], word,
                               __ATOMIC_RELAXED, __HIP_MEMORY_SCOPE_AGENT);
        }
        __syncthreads();           // B2: bounds wave skew; protects hbuf reuse
    }
}

// --------------------- K4: o = [hs_f,hs_b]@Wc^T + bc, log_softmax over C=13
__global__ __launch_bounds__(256) void k_head(
    const float* __restrict__ hs_f, const float* __restrict__ hs_b,
    const float* __restrict__ Wc, const float* __restrict__ bc,
    float* __restrict__ out)
{
    int tid = threadIdx.x, lane = tid & 63, wv = tid >> 6;
    int row = blockIdx.x * 4 + wv;
    const float* src = (lane < 32) ? (hs_f + (size_t)row * HDIM + lane * 24)
                                   : (hs_b + (size_t)row * HDIM + (lane - 32) * 24);
    float hvv[24];
    #pragma unroll
    for (int k = 0; k < 6; k++) {
        float4 f4 = *(const float4*)(src + k * 4);
        hvv[k * 4 + 0] = f4.x; hvv[k * 4 + 1] = f4.y;
        hvv[k * 4 + 2] = f4.z; hvv[k * 4 + 3] = f4.w;
    }
    int off = (lane < 32) ? lane * 24 : 768 + (lane - 32) * 24;
    float o[13];
    #pragma unroll
    for (int n = 0; n < CDIM; n++) {
        const float* wr2 = Wc + (size_t)n * 1536 + off;
        float s0 = 0.f, s1 = 0.f, s2 = 0.f, s3 = 0.f;
        #pragma unroll
        for (int k = 0; k < 6; k++) {
            float4 w4 = *(const float4*)(wr2 + k * 4);
            s0 += w4.x * hvv[k * 4 + 0];
            s1 += w4.y * hvv[k * 4 + 1];
            s2 += w4.z * hvv[k * 4 + 2];
            s3 += w4.w * hvv[k * 4 + 3];
        }
        o[n] = (s0 + s1) + (s2 + s3);
    }
    #pragma unroll
    for (int n = 0; n < CDIM; n++) {
        #pragma unroll
        for (int d = 1; d < 64; d <<= 1) o[n] += __shfl_xor(o[n], d);
        o[n] += bc[n];
    }
    float m = o[0];
    #pragma unroll
    for (int n = 1; n < CDIM; n++) m = fmaxf(m, o[n]);
    float sum = 0.f;
    #pragma unroll
    for (int n = 0; n < CDIM; n++) sum += __expf(o[n] - m);
    float ls = m + __logf(sum);
    if (lane == 0) {
        #pragma unroll
        for (int n = 0; n < CDIM; n++) out[(size_t)row * CDIM + n] = o[n] - ls;
    }
}

// ------------------------------------ K5: Viterbi, single wave, shuffle-based
__global__ __launch_bounds__(64) void k_viterbi(
    const float* __restrict__ ts, const float* __restrict__ st,
    const float* __restrict__ en, const float* __restrict__ tr,
    float* __restrict__ tags_out)
{
    __shared__ unsigned char bp[SEQ - 1][16];
    __shared__ unsigned char path[SEQ];
    int n = threadIdx.x;
    bool act = n < CDIM;
    float trn[CDIM];
    #pragma unroll
    for (int p = 0; p < CDIM; p++) trn[p] = act ? tr[p * CDIM + n] : -1e30f;
    float score = act ? (st[n] + ts[n]) : -1e30f;

    for (int s = 1; s < SEQ; s++) {
        float em = act ? ts[(size_t)s * CDIM + n] : 0.f;
        float sp[CDIM];
        #pragma unroll
        for (int p = 0; p < CDIM; p++) sp[p] = __shfl(score, p);
        float best = -1e30f; int arg = 0;
        #pragma unroll
        for (int p = 0; p < CDIM; p++) {
            float v = sp[p] + trn[p];
            if (v > best) { best = v; arg = p; }   // strict > keeps FIRST max
        }
        score = best + em;
        if (act) bp[s - 1][n] = (unsigned char)arg;
    }
    float fin = act ? (score + en[n]) : -1e30f;
    float fv[CDIM];
    #pragma unroll
    for (int p = 0; p < CDIM; p++) fv[p] = __shfl(fin, p);
    __syncthreads();           // bp writes visible to lane 0 (one wave: cheap)
    if (n == 0) {
        float best = -1e30f; int last = 0;
        #pragma unroll
        for (int p = 0; p < CDIM; p++) { if (fv[p] > best) { best = fv[p]; last = p; } }
        int cur = last;
        path[SEQ - 1] = (unsigned char)cur;
        for (int s = SEQ - 2; s >= 0; s--) { cur = bp[s][cur]; path[s] = (unsigned char)cur; }
    }
    __syncthreads();
    for (int i = n; i < SEQ; i += 64) tags_out[i] = (float)path[i];
}

// --------------------------------------------- fallback if ws is too small
__global__ void k_zero(float* p, int n) {
    int i = blockIdx.x * 256 + threadIdx.x;
    if (i < n) p[i] = 0.f;
}

// ----------------------------------------------------------------- launch
extern "C" void kernel_launch(void* const* d_in, const int* in_sizes, int n_in,
                              void* d_out, int out_size, void* d_ws, size_t ws_size,
                              hipStream_t stream)
{
    const int*   x      = (const int*)d_in[0];
    const int*   casing = (const int*)d_in[1];
    const int*   pos    = (const int*)d_in[2];
    const float* we     = (const float*)d_in[3];
    const float* ce     = (const float*)d_in[4];
    const float* pe     = (const float*)d_in[5];
    const float* Wih_f  = (const float*)d_in[6];
    const float* Whh_f  = (const float*)d_in[7];
    const float* b_f    = (const float*)d_in[8];
    const float* Wih_b  = (const float*)d_in[9];
    const float* Whh_b  = (const float*)d_in[10];
    const float* b_b    = (const float*)d_in[11];
    const float* Wc     = (const float*)d_in[12];
    const float* bc     = (const float*)d_in[13];
    const float* strt   = (const float*)d_in[14];
    const float* endt   = (const float*)d_in[15];
    const float* trans  = (const float*)d_in[16];
    const float* h0     = (const float*)d_in[17];
    const float* c0     = (const float*)d_in[18];

    // ws layout (bytes):
    //   hs_f fp32 6,291,456 @ 0
    //   hs_b fp32 6,291,456 @ 6,291,456
    //   xg_f bf16 12,582,912 @ 12,582,912
    //   xg_b bf16 12,582,912 @ 25,165,824
    //   msg  u64  24,576     @ 37,748,736
    //   abort u32 4          @ 37,773,312
    const size_t need = 37773316;
    if (ws_size < need) {   // clean deterministic failure instead of OOB fault
        k_zero<<<(out_size + 255) / 256, 256, 0, stream>>>((float*)d_out, out_size);
        return;
    }
    char* wsb = (char*)d_ws;
    float* hs_f = (float*)(wsb);
    float* hs_b = (float*)(wsb + 6291456);
    __hip_bfloat16* xg_f = (__hip_bfloat16*)(wsb + 12582912);
    __hip_bfloat16* xg_b = (__hip_bfloat16*)(wsb + 25165824);
    unsigned long long* msg = (unsigned long long*)(wsb + 37748736);
    unsigned* abortw = (unsigned*)(wsb + 37773312);

    hipMemsetAsync(msg, 0, 24576 + 4, stream);   // reset tags + abort (replay-safe)

    k_gemm_xg<<<dim3(G4 / 64, SEQ / 64, 2), 256, 0, stream>>>(
        x, casing, pos, we, ce, pe, Wih_f, b_f, Wih_b, b_b, xg_f, xg_b);
    k_lstm<<<2 * NWG, 1024, 0, stream>>>(
        xg_f, xg_b, Whh_f, Whh_b, h0, c0, hs_f, hs_b, msg, abortw);
    k_head<<<SEQ / 4, 256, 0, stream>>>(hs_f, hs_b, Wc, bc, (float*)d_out);
    k_viterbi<<<1, 64, 0, stream>>>(
        (const float*)d_out, strt, endt, trans, (float*)d_out + (size_t)SEQ * CDIM);
}

// Round 9
// 6050.850 us; speedup vs baseline: 1.2173x; 1.2173x over previous
//
#include <hip/hip_runtime.h>
#include <hip/hip_bf16.h>

// BiLSTM-CRF tagger, MI355X. Round 9: compact bf16 exchange + dual pollers,
// 128x128 fp32 GEMM.
//   K2 fused embed-gather + xg GEMM, 128x128 tile, 8x8 acc/thread (bf16 out)
//   K3 LSTM recurrence: 96 blocks (48/dir) x 1024 thr (16 waves, 1 h-elem/wave).
//      Exchange word: u32 {tag u16 | bf16(h)} (parity double-buffer) -- half
//      the poll lines of the u64 scheme. Waves 0 AND 1 poll (6 loads/lane per
//      round) with selective re-reads, fill hbuf (f32), B1 gates the block.
//      msg store issued before hs store. 2 barriers/step; abort cascade.
//   K4 head + log_softmax -> K5 wave-synchronous Viterbi.

#define SEQ  2048
#define DINW 496
#define HDIM 768
#define G4   3072
#define CDIM 13
#define NWG  48           // workgroups per direction (2*NWG = 96 blocks)
#define JPW  16           // h elements per workgroup (one per wave)
#define DATA_SPIN (1u << 14)

__device__ __forceinline__ float sigf(float x) { return 1.0f / (1.0f + __expf(-x)); }
__device__ __forceinline__ float tanhf_fast(float x) {
    float ax = fabsf(x);
    float e  = __expf(-2.0f * ax);
    float t  = (1.0f - e) / (1.0f + e);
    return copysignf(t, x);
}

// ---- K2: xg = [we[x],ce[casing],pe[pos]] @ Wih^T + b  (bf16 out), 128x128 tile
__global__ __launch_bounds__(256) void k_gemm_xg(
    const int* __restrict__ x, const int* __restrict__ casing, const int* __restrict__ pos,
    const float* __restrict__ we, const float* __restrict__ ce, const float* __restrict__ pe,
    const float* __restrict__ Wih_f, const float* __restrict__ b_f,
    const float* __restrict__ Wih_b, const float* __restrict__ b_b,
    __hip_bfloat16* __restrict__ xg_f, __hip_bfloat16* __restrict__ xg_b)
{
    __shared__ float As[16][132];
    __shared__ float Bs[16][132];
    int dir = blockIdx.z;
    const float* B    = dir ? Wih_b : Wih_f;
    const float* bias = dir ? b_b   : b_f;
    __hip_bfloat16* C = dir ? xg_b  : xg_f;
    int n0 = blockIdx.x * 128, m0 = blockIdx.y * 128;
    int tid = threadIdx.x;
    int r  = tid >> 1, cb = (tid & 1) * 8;     // staging: row r, col-base cb
    int tx = tid & 15, ty = tid >> 4;          // compute: 8x8 at (ty*8, tx*8)

    int m = m0 + r;
    const float* arow_w = we + (size_t)x[m] * 400;
    const float* arow_c = ce + (size_t)casing[m] * 32;
    const float* arow_p = pe + (size_t)pos[m] * 64;
    const float* brow   = B + (size_t)(n0 + r) * DINW;

    float acc[8][8] = {};
    for (int k0 = 0; k0 < DINW; k0 += 16) {
        int c0 = k0 + cb;
        float4 a0, a1, b0, b1;
        // regions 400/432 are multiples of 4: a float4 never straddles
        if (c0 < 400)      a0 = *(const float4*)(arow_w + c0);
        else if (c0 < 432) a0 = *(const float4*)(arow_c + (c0 - 400));
        else               a0 = *(const float4*)(arow_p + (c0 - 432));
        int c4 = c0 + 4;
        if (c4 < 400)      a1 = *(const float4*)(arow_w + c4);
        else if (c4 < 432) a1 = *(const float4*)(arow_c + (c4 - 400));
        else               a1 = *(const float4*)(arow_p + (c4 - 432));
        b0 = *(const float4*)(brow + c0);
        b1 = *(const float4*)(brow + c4);
        __syncthreads();
        As[cb + 0][r] = a0.x; As[cb + 1][r] = a0.y; As[cb + 2][r] = a0.z; As[cb + 3][r] = a0.w;
        As[cb + 4][r] = a1.x; As[cb + 5][r] = a1.y; As[cb + 6][r] = a1.z; As[cb + 7][r] = a1.w;
        Bs[cb + 0][r] = b0.x; Bs[cb + 1][r] = b0.y; Bs[cb + 2][r] = b0.z; Bs[cb + 3][r] = b0.w;
        Bs[cb + 4][r] = b1.x; Bs[cb + 5][r] = b1.y; Bs[cb + 6][r] = b1.z; Bs[cb + 7][r] = b1.w;
        __syncthreads();
        #pragma unroll
        for (int k = 0; k < 16; k++) {
            float4 av0 = *(const float4*)&As[k][ty * 8];
            float4 av1 = *(const float4*)&As[k][ty * 8 + 4];
            float4 bv0 = *(const float4*)&Bs[k][tx * 8];
            float4 bv1 = *(const float4*)&Bs[k][tx * 8 + 4];
            float aa[8] = {av0.x, av0.y, av0.z, av0.w, av1.x, av1.y, av1.z, av1.w};
            float bb[8] = {bv0.x, bv0.y, bv0.z, bv0.w, bv1.x, bv1.y, bv1.z, bv1.w};
            #pragma unroll
            for (int i = 0; i < 8; i++)
                #pragma unroll
                for (int jj = 0; jj < 8; jj++)
                    acc[i][jj] += aa[i] * bb[jj];
        }
    }
    float4 bs0 = *(const float4*)(bias + n0 + tx * 8);
    float4 bs1 = *(const float4*)(bias + n0 + tx * 8 + 4);
    float bb8[8] = {bs0.x, bs0.y, bs0.z, bs0.w, bs1.x, bs1.y, bs1.z, bs1.w};
    #pragma unroll
    for (int i = 0; i < 8; i++) {
        int row = m0 + ty * 8 + i;
        union { __hip_bfloat16 h[4]; ushort4 u; } c0v, c1v;
        #pragma unroll
        for (int jj = 0; jj < 4; jj++) {
            c0v.h[jj] = __float2bfloat16(acc[i][jj] + bb8[jj]);
            c1v.h[jj] = __float2bfloat16(acc[i][jj + 4] + bb8[jj + 4]);
        }
        *(ushort4*)(C + (size_t)row * G4 + n0 + tx * 8)     = c0v.u;
        *(ushort4*)(C + (size_t)row * G4 + n0 + tx * 8 + 4) = c1v.u;
    }
}

// ------------------------------------------------------- K3: LSTM recurrence
// msg[dir][parity][768] u32 {tag<<16 | bf16bits(h)}: h(t) -> parity t&1,
// tag t+1 (t+1 <= 2048 << 65536: no wrap). Consumer step t polls parity
// (t&1)^1 for tag == t; waves 0 and 1 each poll half with selective re-reads.
// Overwrite-safety/deadlock-freedom (all-to-all gate): P stores tag t+2 only
// after P passed step-t+1's B1, i.e. after BOTH its pollers consumed ALL
// tag-(t+1) words; a block emits tag t+1 only after fully consuming tag t.
__global__ __launch_bounds__(1024) void k_lstm(
    const __hip_bfloat16* __restrict__ xg_f, const __hip_bfloat16* __restrict__ xg_b,
    const float* __restrict__ Whh_f, const float* __restrict__ Whh_b,
    const float* __restrict__ h0, const float* __restrict__ c0v,
    float* __restrict__ hs_f, float* __restrict__ hs_b,
    unsigned* __restrict__ msg, unsigned* __restrict__ abortw)
{
    __shared__ float hbuf[2][HDIM];
    __shared__ unsigned sdead;

    int wg = blockIdx.x;
    int dir = wg & 1, slot = wg >> 1;          // slot 0..47
    const __hip_bfloat16* xg = dir ? xg_b : xg_f;
    const float* Whh = dir ? Whh_b : Whh_f;
    float* hs        = dir ? hs_b  : hs_f;
    unsigned* mdir = msg + (size_t)dir * 2 * HDIM;

    int tid = threadIdx.x, lane = tid & 63, wv = tid >> 6;   // wv 0..15
    int q = lane >> 4, gl = lane & 15;
    int j = slot * JPW + wv;

    // this lane's Whh slice: row q*768+j, cols gl*4 + m*64 + e
    float w[48];
    const float* wr = Whh + (size_t)(q * HDIM + j) * HDIM;
    #pragma unroll
    for (int m = 0; m < 12; m++) {
        float4 f4 = *(const float4*)(wr + gl * 4 + m * 64);
        w[m * 4 + 0] = f4.x; w[m * 4 + 1] = f4.y;
        w[m * 4 + 2] = f4.z; w[m * 4 + 3] = f4.w;
    }
    float cst = c0v[dir * HDIM + j];

    if (tid == 0) sdead = 0;

    for (int t = 0; t < SEQ; t++) {
        int xrow = dir ? (SEQ - 1 - t) : t;
        const __hip_bfloat16* xga = xg + (size_t)xrow * G4 + j;
        float xv0 = __bfloat162float(xga[0]);
        float xv1 = __bfloat162float(xga[HDIM]);
        float xv2 = __bfloat162float(xga[2 * HDIM]);
        float xv3 = __bfloat162float(xga[3 * HDIM]);

        int par = (t & 1) ^ 1;   // parity slot holding h(t-1)

        if (wv < 2) {            // dual pollers: wave0 words 0..383, wave1 384..767
            int base = wv * 6;
            if (t == 0) {
                #pragma unroll
                for (int m = 0; m < 6; m++)
                    hbuf[1][(base + m) * 64 + lane] = h0[dir * HDIM + (base + m) * 64 + lane];
            } else {
                const unsigned* g = mdir + (size_t)par * HDIM;
                unsigned vals[6];
                unsigned fresh = 0, rounds = 0;
                bool dead = false;
                for (;;) {
                    #pragma unroll
                    for (int m = 0; m < 6; m++)
                        if (!(fresh & (1u << m)))
                            vals[m] = __hip_atomic_load(&g[(base + m) * 64 + lane],
                                        __ATOMIC_RELAXED, __HIP_MEMORY_SCOPE_AGENT);
                    #pragma unroll
                    for (int m = 0; m < 6; m++)
                        if ((vals[m] >> 16) == (unsigned)t) fresh |= (1u << m);
                    if (__all(fresh == 0x3Fu)) break;
                    unsigned ab = __hip_atomic_load(abortw,
                                    __ATOMIC_RELAXED, __HIP_MEMORY_SCOPE_AGENT);
                    if (ab || ++rounds >= DATA_SPIN) { dead = true; break; }
                }
                #pragma unroll
                for (int m = 0; m < 6; m++) {
                    union { unsigned u; float f; } cvt;
                    cvt.u = (vals[m] & 0xFFFFu) << 16;   // bf16 -> f32 (exact)
                    hbuf[par][(base + m) * 64 + lane] = cvt.f;
                }
                if (dead && lane == 0) {   // cascade shutdown, bounded everywhere
                    __hip_atomic_store(abortw, 1u,
                                       __ATOMIC_RELAXED, __HIP_MEMORY_SCOPE_AGENT);
                    sdead = 1;
                }
            }
        }

        __syncthreads();           // B1: hbuf ready (and sdead visible)
        if (sdead) break;          // block-uniform bail

        // matvec slice over this lane's 48 columns from LDS
        float acc = 0.f;
        #pragma unroll
        for (int m = 0; m < 12; m++) {
            float4 f4 = *(const float4*)&hbuf[par][gl * 4 + m * 64];
            acc += w[m * 4 + 0] * f4.x + w[m * 4 + 1] * f4.y
                 + w[m * 4 + 2] * f4.z + w[m * 4 + 3] * f4.w;
        }
        acc += __shfl_xor(acc, 1);
        acc += __shfl_xor(acc, 2);
        acc += __shfl_xor(acc, 4);
        acc += __shfl_xor(acc, 8);
        float si = __shfl(acc, 0),  sf = __shfl(acc, 16);
        float sg = __shfl(acc, 32), so = __shfl(acc, 48);

        float gi = sigf(xv0 + si), gf = sigf(xv1 + sf);
        float gg = tanhf_fast(xv2 + sg), go = sigf(xv3 + so);
        cst = gf * cst + gi * gg;
        float h = go * tanhf_fast(cst);

        if (lane == 0) {
            union { __hip_bfloat16 b; unsigned short u; } cv;
            cv.b = __float2bfloat16(h);
            unsigned word = ((unsigned)(t + 1) << 16) | (unsigned)cv.u;
            __hip_atomic_store(&mdir[(size_t)(t & 1) * HDIM + j], word,
                               __ATOMIC_RELAXED, __HIP_MEMORY_SCOPE_AGENT);  // first!
            int hrow = dir ? (SEQ - 1 - t) : t;
            hs[(size_t)hrow * HDIM + j] = h;          // for K4 (cross-dispatch)
        }
        __syncthreads();           // B2: bounds wave skew; protects hbuf reuse
    }
}

// --------------------- K4: o = [hs_f,hs_b]@Wc^T + bc, log_softmax over C=13
__global__ __launch_bounds__(256) void k_head(
    const float* __restrict__ hs_f, const float* __restrict__ hs_b,
    const float* __restrict__ Wc, const float* __restrict__ bc,
    float* __restrict__ out)
{
    int tid = threadIdx.x, lane = tid & 63, wv = tid >> 6;
    int row = blockIdx.x * 4 + wv;
    const float* src = (lane < 32) ? (hs_f + (size_t)row * HDIM + lane * 24)
                                   : (hs_b + (size_t)row * HDIM + (lane - 32) * 24);
    float hvv[24];
    #pragma unroll
    for (int k = 0; k < 6; k++) {
        float4 f4 = *(const float4*)(src + k * 4);
        hvv[k * 4 + 0] = f4.x; hvv[k * 4 + 1] = f4.y;
        hvv[k * 4 + 2] = f4.z; hvv[k * 4 + 3] = f4.w;
    }
    int off = (lane < 32) ? lane * 24 : 768 + (lane - 32) * 24;
    float o[13];
    #pragma unroll
    for (int n = 0; n < CDIM; n++) {
        const float* wr2 = Wc + (size_t)n * 1536 + off;
        float s0 = 0.f, s1 = 0.f, s2 = 0.f, s3 = 0.f;
        #pragma unroll
        for (int k = 0; k < 6; k++) {
            float4 w4 = *(const float4*)(wr2 + k * 4);
            s0 += w4.x * hvv[k * 4 + 0];
            s1 += w4.y * hvv[k * 4 + 1];
            s2 += w4.z * hvv[k * 4 + 2];
            s3 += w4.w * hvv[k * 4 + 3];
        }
        o[n] = (s0 + s1) + (s2 + s3);
    }
    #pragma unroll
    for (int n = 0; n < CDIM; n++) {
        #pragma unroll
        for (int d = 1; d < 64; d <<= 1) o[n] += __shfl_xor(o[n], d);
        o[n] += bc[n];
    }
    float m = o[0];
    #pragma unroll
    for (int n = 1; n < CDIM; n++) m = fmaxf(m, o[n]);
    float sum = 0.f;
    #pragma unroll
    for (int n = 0; n < CDIM; n++) sum += __expf(o[n] - m);
    float ls = m + __logf(sum);
    if (lane == 0) {
        #pragma unroll
        for (int n = 0; n < CDIM; n++) out[(size_t)row * CDIM + n] = o[n] - ls;
    }
}

// ------------------------------------ K5: Viterbi, single wave, shuffle-based
__global__ __launch_bounds__(64) void k_viterbi(
    const float* __restrict__ ts, const float* __restrict__ st,
    const float* __restrict__ en, const float* __restrict__ tr,
    float* __restrict__ tags_out)
{
    __shared__ unsigned char bp[SEQ - 1][16];
    __shared__ unsigned char path[SEQ];
    int n = threadIdx.x;
    bool act = n < CDIM;
    float trn[CDIM];
    #pragma unroll
    for (int p = 0; p < CDIM; p++) trn[p] = act ? tr[p * CDIM + n] : -1e30f;
    float score = act ? (st[n] + ts[n]) : -1e30f;

    for (int s = 1; s < SEQ; s++) {
        float em = act ? ts[(size_t)s * CDIM + n] : 0.f;
        float sp[CDIM];
        #pragma unroll
        for (int p = 0; p < CDIM; p++) sp[p] = __shfl(score, p);
        float best = -1e30f; int arg = 0;
        #pragma unroll
        for (int p = 0; p < CDIM; p++) {
            float v = sp[p] + trn[p];
            if (v > best) { best = v; arg = p; }   // strict > keeps FIRST max
        }
        score = best + em;
        if (act) bp[s - 1][n] = (unsigned char)arg;
    }
    float fin = act ? (score + en[n]) : -1e30f;
    float fv[CDIM];
    #pragma unroll
    for (int p = 0; p < CDIM; p++) fv[p] = __shfl(fin, p);
    __syncthreads();           // bp writes visible to lane 0 (one wave: cheap)
    if (n == 0) {
        float best = -1e30f; int last = 0;
        #pragma unroll
        for (int p = 0; p < CDIM; p++) { if (fv[p] > best) { best = fv[p]; last = p; } }
        int cur = last;
        path[SEQ - 1] = (unsigned char)cur;
        for (int s = SEQ - 2; s >= 0; s--) { cur = bp[s][cur]; path[s] = (unsigned char)cur; }
    }
    __syncthreads();
    for (int i = n; i < SEQ; i += 64) tags_out[i] = (float)path[i];
}

// --------------------------------------------- fallback if ws is too small
__global__ void k_zero(float* p, int n) {
    int i = blockIdx.x * 256 + threadIdx.x;
    if (i < n) p[i] = 0.f;
}

// ----------------------------------------------------------------- launch
extern "C" void kernel_launch(void* const* d_in, const int* in_sizes, int n_in,
                              void* d_out, int out_size, void* d_ws, size_t ws_size,
                              hipStream_t stream)
{
    const int*   x      = (const int*)d_in[0];
    const int*   casing = (const int*)d_in[1];
    const int*   pos    = (const int*)d_in[2];
    const float* we     = (const float*)d_in[3];
    const float* ce     = (const float*)d_in[4];
    const float* pe     = (const float*)d_in[5];
    const float* Wih_f  = (const float*)d_in[6];
    const float* Whh_f  = (const float*)d_in[7];
    const float* b_f    = (const float*)d_in[8];
    const float* Wih_b  = (const float*)d_in[9];
    const float* Whh_b  = (const float*)d_in[10];
    const float* b_b    = (const float*)d_in[11];
    const float* Wc     = (const float*)d_in[12];
    const float* bc     = (const float*)d_in[13];
    const float* strt   = (const float*)d_in[14];
    const float* endt   = (const float*)d_in[15];
    const float* trans  = (const float*)d_in[16];
    const float* h0     = (const float*)d_in[17];
    const float* c0     = (const float*)d_in[18];

    // ws layout (bytes):
    //   hs_f fp32 6,291,456 @ 0
    //   hs_b fp32 6,291,456 @ 6,291,456
    //   xg_f bf16 12,582,912 @ 12,582,912
    //   xg_b bf16 12,582,912 @ 25,165,824
    //   msg  u32  12,288     @ 37,748,736
    //   abort u32 4          @ 37,761,024
    const size_t need = 37761028;
    if (ws_size < need) {   // clean deterministic failure instead of OOB fault
        k_zero<<<(out_size + 255) / 256, 256, 0, stream>>>((float*)d_out, out_size);
        return;
    }
    char* wsb = (char*)d_ws;
    float* hs_f = (float*)(wsb);
    float* hs_b = (float*)(wsb + 6291456);
    __hip_bfloat16* xg_f = (__hip_bfloat16*)(wsb + 12582912);
    __hip_bfloat16* xg_b = (__hip_bfloat16*)(wsb + 25165824);
    unsigned* msg = (unsigned*)(wsb + 37748736);
    unsigned* abortw = (unsigned*)(wsb + 37761024);

    hipMemsetAsync(msg, 0, 12288 + 4, stream);   // reset tags + abort (replay-safe)

    k_gemm_xg<<<dim3(G4 / 128, SEQ / 128, 2), 256, 0, stream>>>(
        x, casing, pos, we, ce, pe, Wih_f, b_f, Wih_b, b_b, xg_f, xg_b);
    k_lstm<<<2 * NWG, 1024, 0, stream>>>(
        xg_f, xg_b, Whh_f, Whh_b, h0, c0, hs_f, hs_b, msg, abortw);
    k_head<<<SEQ / 4, 256, 0, stream>>>(hs_f, hs_b, Wc, bc, (float*)d_out);
    k_viterbi<<<1, 64, 0, stream>>>(
        (const float*)d_out, strt, endt, trans, (float*)d_out + (size_t)SEQ * CDIM);
}